// Round 9
// baseline (206.280 us; speedup 1.0000x reference)
//
#include <hip/hip_runtime.h>
#include <math.h>

#define B_ 2
#define T_ 2048
#define C_ 1024
#define H_ 16
#define HD_ 64
#define M_ (B_*T_)

typedef _Float16 half2v __attribute__((ext_vector_type(2)));
typedef _Float16 half4v __attribute__((ext_vector_type(4)));
typedef _Float16 half8v __attribute__((ext_vector_type(8)));
typedef float f32x4 __attribute__((ext_vector_type(4)));

#define GLD_LDS(gp, lp) \
  __builtin_amdgcn_global_load_lds( \
      (const __attribute__((address_space(1))) void*)(gp), \
      (__attribute__((address_space(3))) void*)(lp), 16, 0, 0)

// ---------------------------------------------------------------------------
// Fused prep: fp32->f16 cast of x (blocks 0..2047, 32 B/thread), 4 weight
// transposes (blocks 2048..6143), bias concat (blocks 6144..6155).
// ---------------------------------------------------------------------------
__global__ __launch_bounds__(256) void prep_kernel(
    const float* __restrict__ x,
    const float* __restrict__ Wq, const float* __restrict__ Wk,
    const float* __restrict__ Wv, const float* __restrict__ Wo,
    const float* __restrict__ bq, const float* __restrict__ bk,
    const float* __restrict__ bv,
    _Float16* __restrict__ xh, _Float16* __restrict__ Wt3,
    _Float16* __restrict__ Wot, float* __restrict__ b3)
{
  __shared__ float tile[32][33];
  const int blk = blockIdx.x, thr = threadIdx.x;
  if (blk < 2048) {
    int j = blk * 512 + thr * 2;          // float4 index, this thread: j, j+1
    float4 v0 = ((const float4*)x)[j];
    float4 v1 = ((const float4*)x)[j + 1];
    half8v h;
    h[0] = (_Float16)v0.x; h[1] = (_Float16)v0.y;
    h[2] = (_Float16)v0.z; h[3] = (_Float16)v0.w;
    h[4] = (_Float16)v1.x; h[5] = (_Float16)v1.y;
    h[6] = (_Float16)v1.z; h[7] = (_Float16)v1.w;
    *(half8v*)(xh + (size_t)j * 4) = h;
  } else if (blk < 6144) {
    int zz = (blk - 2048) >> 10;      // which W
    int bxy = (blk - 2048) & 1023;
    const float* W; _Float16* Wt;
    switch (zz) {
      case 0:  W = Wq; Wt = Wt3; break;
      case 1:  W = Wk; Wt = Wt3 + (size_t)1024 * 1024; break;
      case 2:  W = Wv; Wt = Wt3 + (size_t)2048 * 1024; break;
      default: W = Wo; Wt = Wot; break;
    }
    const int n0 = (bxy & 31) * 32, k0 = (bxy >> 5) * 32;
    const int tx = thr & 31, ty = thr >> 5;  // 32 x 8
#pragma unroll
    for (int r = 0; r < 4; r++) {
      int k = ty + r * 8;
      tile[k][tx] = W[(size_t)(k0 + k) * C_ + n0 + tx];
    }
    __syncthreads();
#pragma unroll
    for (int r = 0; r < 4; r++) {
      int n = ty + r * 8;
      Wt[(size_t)(n0 + n) * C_ + k0 + tx] = (_Float16)tile[tx][n];
    }
  } else {
    int i = (blk - 6144) * 256 + thr;  // 0..3071
    const float* s = (i < 1024) ? bq : ((i < 2048) ? bk : bv);
    b3[i] = s[i & 1023];
  }
}

// ---------------------------------------------------------------------------
// f16 MFMA GEMM: Out[M,N] = A[M,1024] @ Wt[N,1024]^T + bias.
// BK=32, 256 threads = 4 waves (2x2); wave tile (BM/2)x(BN/2).
// Staging via global_load_lds width=16 (m97 pattern).
// EPI 0: fused QKV epilogue. Q (scaled 0.125*log2e) and K: plain 2-B stores.
// V: packed 8-B stores to V^T.  EPI 1: fp32 out + bias (of).
// ---------------------------------------------------------------------------
template <int BM, int BN, int EPI>
__global__ __launch_bounds__(256) void gemm_f16_kernel(
    const _Float16* __restrict__ A, const _Float16* __restrict__ Bw,
    const float* __restrict__ bias,
    _Float16* __restrict__ o0, _Float16* __restrict__ o1,
    _Float16* __restrict__ o2, float* __restrict__ of)
{
  constexpr int FM = BM / 32, FN = BN / 32;
  __shared__ __align__(16) _Float16 As[BM * 32];
  __shared__ __align__(16) _Float16 Bs[BN * 32];
  const int t = threadIdx.x;
  const int w = t >> 6, lane = t & 63, l15 = lane & 15, quad = lane >> 4;
  const int wm = (w & 1) * (BM / 2), wn = (w >> 1) * (BN / 2);
  const int bm = blockIdx.y * BM, bn = blockIdx.x * BN;
  const int lrow = lane >> 2, lcol = (lane & 3) * 8;  // staging: 16 rows/call

  f32x4 acc[FM][FN];
#pragma unroll
  for (int i = 0; i < FM; i++)
#pragma unroll
    for (int j = 0; j < FN; j++) acc[i][j] = (f32x4){0.f, 0.f, 0.f, 0.f};

  for (int k0 = 0; k0 < 1024; k0 += 32) {
#pragma unroll
    for (int i = 0; i < BM / 64; i++) {
      int ca = w + 4 * i;
      int row = ca * 16 + lrow;
      GLD_LDS(A + (size_t)(bm + row) * 1024 + k0 + lcol, As + ca * 512);
    }
#pragma unroll
    for (int i = 0; i < BN / 64; i++) {
      int cb = w + 4 * i;
      int row = cb * 16 + lrow;
      GLD_LDS(Bw + (size_t)(bn + row) * 1024 + k0 + lcol, Bs + cb * 512);
    }
    __syncthreads();

    half8v af[FM], bf[FN];
#pragma unroll
    for (int mt = 0; mt < FM; mt++)
      af[mt] = *(const half8v*)(As + (wm + mt * 16 + l15) * 32 + quad * 8);
#pragma unroll
    for (int nt = 0; nt < FN; nt++)
      bf[nt] = *(const half8v*)(Bs + (wn + nt * 16 + l15) * 32 + quad * 8);
#pragma unroll
    for (int mt = 0; mt < FM; mt++)
#pragma unroll
      for (int nt = 0; nt < FN; nt++)
        acc[mt][nt] = __builtin_amdgcn_mfma_f32_16x16x32_f16(
            af[mt], bf[nt], acc[mt][nt], 0, 0, 0);
    __syncthreads();
  }

  // Epilogue. C/D layout: col = l15 (n), row = quad*4 + r (m).
#pragma unroll
  for (int mt = 0; mt < FM; mt++)
#pragma unroll
    for (int nt = 0; nt < FN; nt++) {
      int n = bn + wn + nt * 16 + l15;
      float bv = bias[n];
      if (EPI == 0 && bn >= 2048) {
        // V region: pack r=0..3 (consecutive t) -> one 8-B store to V^T.
        int dg = n - 2048;
        int hh = dg >> 6, hd = dg & 63;
        int m0 = bm + wm + mt * 16 + quad * 4;
        int bb = m0 >> 11, tt = m0 & 2047;
        half2v p01 = __builtin_bit_cast(half2v,
            __builtin_amdgcn_cvt_pkrtz(acc[mt][nt][0] + bv, acc[mt][nt][1] + bv));
        half2v p23 = __builtin_bit_cast(half2v,
            __builtin_amdgcn_cvt_pkrtz(acc[mt][nt][2] + bv, acc[mt][nt][3] + bv));
        half4v pk = __builtin_shufflevector(p01, p23, 0, 1, 2, 3);
        *(half4v*)(o2 + (((size_t)(bb * H_ + hh) * 64 + hd) * 2048 + tt)) = pk;
      } else {
#pragma unroll
        for (int r = 0; r < 4; r++) {
          int m = bm + wm + mt * 16 + quad * 4 + r;
          float v = acc[mt][nt][r] + bv;
          if (EPI == 0) {
            if (bn < 1024) {
              // Q pre-scaled by 0.125 * log2(e) for base-2 softmax.
              o0[(size_t)m * 1024 + n] = (_Float16)(v * 0.180336884f);
            } else {
              o1[(size_t)m * 1024 + (n - 1024)] = (_Float16)v;    // K
            }
          } else {
            of[(size_t)m * 1024 + n] = v;
          }
        }
      }
    }
}

// ---------------------------------------------------------------------------
// MFMA flash attention (no mask, per reference). Grid (T/128, H, B), 512 thr.
// V18 = round-6 frame EXACTLY (best measured 62.0 us; T14 variants proven
// neutral in r8 -- staging latency is hidden by inter-wave overlap) with two
// in-place softmax VALU reductions:
//  (T13) defer-max: skip the alpha-rescale (1 exp2 + 16 o-muls + l-mul) when
//        __all(tmax - m_run <= 8). p bounded by 2^8 = 256; psum <= 32768;
//        fp32 accumulation has ample headroom. ~15/16 tiles skip.
//  (T17) max3-structured 32-element max (pairs + fused triple -> v_max3).
// Carried wins: PV x32 dual-half4v (r6), bijective XCD swizzle (r5:
// FETCH 69.7->12.3 MB), s_setprio around MFMA clusters (T5).
// LDS: Ks[128][68] + Vs[64][132] = 34.3 KB (2 blocks/CU proven).
// Wave w (0..7) owns q-cols qt*128 + w*16 + l15. Base-2 softmax.
// ---------------------------------------------------------------------------
__global__ __launch_bounds__(512) void attn_f16_kernel(
    const _Float16* __restrict__ Qh, const _Float16* __restrict__ Kh,
    const _Float16* __restrict__ Vt, _Float16* __restrict__ Yh)
{
  __shared__ __align__(16) _Float16 Ks[128 * 68];   // [key][d], 136-B rows
  __shared__ __align__(16) _Float16 Vs[64 * 132];   // [d][t], 264-B rows
  const int t = threadIdx.x;
  const int w = t >> 6, lane = t & 63, l15 = lane & 15, quad = lane >> 4;
  // XCD-aware bijective remap of the 512 linear block ids (x fastest):
  // swz = (lin%8)*64 + lin/8 -> 64-consecutive-work chunks per XCD,
  // each chunk = 4 complete (b,h) groups (their K/V stay in one L2).
  const int lin = blockIdx.x + 16 * blockIdx.y + 256 * blockIdx.z;
  const int swz = (lin & 7) * 64 + (lin >> 3);
  const int qt = swz & 15, h = (swz >> 4) & 15, b = swz >> 8;
  const int qg = qt * 128 + w * 16 + l15;
  const size_t qoff = ((size_t)(b * T_ + qg)) * C_ + h * HD_;

  half8v qf[2];
  qf[0] = *(const half8v*)(Qh + qoff + quad * 8);
  qf[1] = *(const half8v*)(Qh + qoff + 32 + quad * 8);

  f32x4 o[4];
#pragma unroll
  for (int i = 0; i < 4; i++) o[i] = (f32x4){0.f, 0.f, 0.f, 0.f};
  float m_run = -INFINITY, l_run = 0.f;

  const size_t kbase = ((size_t)b * T_) * C_ + h * HD_;
  const size_t vbase = ((size_t)(b * H_ + h)) * HD_ * 2048;

  for (int kt0 = 0; kt0 < T_; kt0 += 128) {
    // Stage K: 128 keys x 64 d = 1024 16-B chunks (2 per thread).
#pragma unroll
    for (int i = 0; i < 2; i++) {
      int slot = t + i * 512;          // 0..1023
      int row = slot >> 3, cp = slot & 7;
      *(uint4*)((char*)Ks + row * 136 + cp * 16) =
          *(const uint4*)(Kh + kbase + (size_t)(kt0 + row) * C_ + cp * 8);
    }
    // Stage V^T: 64 d x 128 t = 1024 16-B chunks (2 per thread).
#pragma unroll
    for (int i = 0; i < 2; i++) {
      int slot = t + i * 512;          // 0..1023
      int row = slot >> 4, cp = slot & 15;
      *(uint4*)((char*)Vs + row * 264 + cp * 16) =
          *(const uint4*)(Vt + vbase + (size_t)row * 2048 + kt0 + cp * 8);
    }
    __syncthreads();

    // S^T tiles: 8 key-tiles x 2 d-steps of 16x16x32 (unpermuted).
    f32x4 s[8];
    __builtin_amdgcn_s_setprio(1);
#pragma unroll
    for (int kt = 0; kt < 8; kt++) {
      s[kt] = (f32x4){0.f, 0.f, 0.f, 0.f};
      int key = kt * 16 + l15;
#pragma unroll
      for (int ks = 0; ks < 2; ks++) {
        half8v kf = *(const half8v*)((char*)Ks + key * 136 + (ks * 4 + quad) * 16);
        s[kt] = __builtin_amdgcn_mfma_f32_16x16x32_f16(kf, qf[ks], s[kt], 0, 0, 0);
      }
    }
    __builtin_amdgcn_s_setprio(0);

    // Online softmax (base-2) over the 128 keys, per q column = l15.
    // T17: pair-max then fused triple (v_max3).
    float tmax = -INFINITY;
#pragma unroll
    for (int kt = 0; kt < 8; kt++) {
      float t01 = fmaxf(s[kt][0], s[kt][1]);
      float t23 = fmaxf(s[kt][2], s[kt][3]);
      tmax = fmaxf(fmaxf(t01, t23), tmax);
    }
    tmax = fmaxf(tmax, __shfl_xor(tmax, 16));
    tmax = fmaxf(tmax, __shfl_xor(tmax, 32));

    // T13 defer-max: rescale only when some q-row's max grew past m_run + 8.
    // Skip path keeps m_run; p <= 2^8, fp32 accum headroom is ample.
    if (!__all(tmax - m_run <= 8.0f)) {
      float mnew = fmaxf(m_run, tmax);
      float alpha = __builtin_amdgcn_exp2f(m_run - mnew);
      l_run *= alpha;
#pragma unroll
      for (int dt = 0; dt < 4; dt++) o[dt] *= alpha;
      m_run = mnew;
    }

    float psum = 0.f;
    half4v pf[8];
#pragma unroll
    for (int kt = 0; kt < 8; kt++) {
      float p0 = __builtin_amdgcn_exp2f(s[kt][0] - m_run);
      float p1 = __builtin_amdgcn_exp2f(s[kt][1] - m_run);
      float p2 = __builtin_amdgcn_exp2f(s[kt][2] - m_run);
      float p3 = __builtin_amdgcn_exp2f(s[kt][3] - m_run);
      psum += (p0 + p1) + (p2 + p3);
      half2v pk01 = __builtin_bit_cast(half2v, __builtin_amdgcn_cvt_pkrtz(p0, p1));
      half2v pk23 = __builtin_bit_cast(half2v, __builtin_amdgcn_cvt_pkrtz(p2, p3));
      pf[kt] = __builtin_shufflevector(pk01, pk23, 0, 1, 2, 3);
    }
    psum += __shfl_xor(psum, 16);
    psum += __shfl_xor(psum, 32);
    l_run += psum;

    // PV: o^T[d][q] += V^T x P, 4 d-tiles x 4 key-groups of 16x16x32.
    // pf[2p] holds P[32p+4q+(0..3)][q], pf[2p+1] holds P[32p+16+4q+(0..3)][q]
    // -> concat is the x32 B-operand (k=8q+j). Matching V^T A-operand:
    // two half4v at d*264 + p*64 + q*8 (+32) -- same addresses round 1 read.
    __builtin_amdgcn_s_setprio(1);
#pragma unroll
    for (int dt = 0; dt < 4; dt++) {
      int d = dt * 16 + l15;
#pragma unroll
      for (int p = 0; p < 4; p++) {
        half4v v0 = *(const half4v*)((char*)Vs + d * 264 + p * 64 + quad * 8);
        half4v v1 = *(const half4v*)((char*)Vs + d * 264 + p * 64 + 32 + quad * 8);
        half8v vf = __builtin_shufflevector(v0, v1, 0, 1, 2, 3, 4, 5, 6, 7);
        half8v pf8 = __builtin_shufflevector(pf[2 * p], pf[2 * p + 1],
                                             0, 1, 2, 3, 4, 5, 6, 7);
        o[dt] = __builtin_amdgcn_mfma_f32_16x16x32_f16(vf, pf8, o[dt], 0, 0, 0);
      }
    }
    __builtin_amdgcn_s_setprio(0);
    __syncthreads();
  }

  float inv = 1.0f / l_run;
#pragma unroll
  for (int dt = 0; dt < 4; dt++) {
    half4v yv;
#pragma unroll
    for (int r = 0; r < 4; r++) yv[r] = (_Float16)(o[dt][r] * inv);
    *(half4v*)(Yh + qoff + dt * 16 + quad * 4) = yv;  // row q, cols h*64+d..
  }
}

// ---------------------------------------------------------------------------
extern "C" void kernel_launch(void* const* d_in, const int* in_sizes, int n_in,
                              void* d_out, int out_size, void* d_ws, size_t ws_size,
                              hipStream_t stream) {
  const float* x  = (const float*)d_in[0];
  const float* Wq = (const float*)d_in[1];
  const float* bq = (const float*)d_in[2];
  const float* Wk = (const float*)d_in[3];
  const float* bk = (const float*)d_in[4];
  const float* Wv = (const float*)d_in[5];
  const float* bv = (const float*)d_in[6];
  const float* Wo = (const float*)d_in[7];
  const float* bo = (const float*)d_in[8];
  float* out = (float*)d_out;

  // Workspace carve-up (bytes). Each f16 plane M_*C_ = 8 MB.
  char* ws = (char*)d_ws;
  _Float16* xh   = (_Float16*)(ws);                        // 8 MB
  _Float16* Qh   = (_Float16*)(ws + (((size_t)8)  << 20)); // 8 MB
  _Float16* Kh   = (_Float16*)(ws + (((size_t)16) << 20)); // 8 MB
  _Float16* Vt   = (_Float16*)(ws + (((size_t)24) << 20)); // 8 MB  [b,h,d,t]
  _Float16* Yh   = (_Float16*)(ws + (((size_t)32) << 20)); // 8 MB
  _Float16* Wt3  = (_Float16*)(ws + (((size_t)40) << 20)); // 6 MB  [3072][1024]
  _Float16* Wot  = (_Float16*)(ws + (((size_t)46) << 20)); // 2 MB  [1024][1024]
  float*    b3   = (float*)   (ws + (((size_t)48) << 20)); // 12 KB

  prep_kernel<<<6156, 256, 0, stream>>>(x, Wq, Wk, Wv, Wo, bq, bk, bv,
                                        xh, Wt3, Wot, b3);

  // Fused QKV projection: [4096,1024] @ [1024,3072] -> Q,K (f16) + V^T (f16).
  gemm_f16_kernel<128, 128, 0><<<dim3(24, 32), 256, 0, stream>>>(
      xh, Wt3, b3, Qh, Kh, Vt, nullptr);

  attn_f16_kernel<<<dim3(T_ / 128, H_, B_), 512, 0, stream>>>(Qh, Kh, Vt, Yh);

  // Output projection: Yh @ Wot^T + bo -> fp32 out.
  gemm_f16_kernel<64, 128, 1><<<dim3(8, 64), 256, 0, stream>>>(
      Yh, Wot, bo, nullptr, nullptr, nullptr, out);
}

// Round 10
// 196.267 us; speedup vs baseline: 1.0510x; 1.0510x over previous
//
#include <hip/hip_runtime.h>
#include <math.h>

#define B_ 2
#define T_ 2048
#define C_ 1024
#define H_ 16
#define HD_ 64
#define M_ (B_*T_)

typedef _Float16 half2v __attribute__((ext_vector_type(2)));
typedef _Float16 half4v __attribute__((ext_vector_type(4)));
typedef _Float16 half8v __attribute__((ext_vector_type(8)));
typedef float f32x4 __attribute__((ext_vector_type(4)));

#define GLD_LDS(gp, lp) \
  __builtin_amdgcn_global_load_lds( \
      (const __attribute__((address_space(1))) void*)(gp), \
      (__attribute__((address_space(3))) void*)(lp), 16, 0, 0)

// ---------------------------------------------------------------------------
// Fused prep: fp32->f16 cast of x (blocks 0..4095), 4 weight transposes
// (blocks 4096..8191), bias concat (blocks 8192..8203). One launch.
// ---------------------------------------------------------------------------
__global__ __launch_bounds__(256) void prep_kernel(
    const float* __restrict__ x,
    const float* __restrict__ Wq, const float* __restrict__ Wk,
    const float* __restrict__ Wv, const float* __restrict__ Wo,
    const float* __restrict__ bq, const float* __restrict__ bk,
    const float* __restrict__ bv,
    _Float16* __restrict__ xh, _Float16* __restrict__ Wt3,
    _Float16* __restrict__ Wot, float* __restrict__ b3)
{
  __shared__ float tile[32][33];
  const int blk = blockIdx.x, thr = threadIdx.x;
  if (blk < 4096) {
    int i = blk * 256 + thr;
    float4 v = ((const float4*)x)[i];
    half4v h; h[0] = (_Float16)v.x; h[1] = (_Float16)v.y;
    h[2] = (_Float16)v.z; h[3] = (_Float16)v.w;
    ((half4v*)xh)[i] = h;
  } else if (blk < 8192) {
    int zz = (blk - 4096) >> 10;      // which W
    int bxy = (blk - 4096) & 1023;
    const float* W; _Float16* Wt;
    switch (zz) {
      case 0:  W = Wq; Wt = Wt3; break;
      case 1:  W = Wk; Wt = Wt3 + (size_t)1024 * 1024; break;
      case 2:  W = Wv; Wt = Wt3 + (size_t)2048 * 1024; break;
      default: W = Wo; Wt = Wot; break;
    }
    const int n0 = (bxy & 31) * 32, k0 = (bxy >> 5) * 32;
    const int tx = thr & 31, ty = thr >> 5;  // 32 x 8
#pragma unroll
    for (int r = 0; r < 4; r++) {
      int k = ty + r * 8;
      tile[k][tx] = W[(size_t)(k0 + k) * C_ + n0 + tx];
    }
    __syncthreads();
#pragma unroll
    for (int r = 0; r < 4; r++) {
      int n = ty + r * 8;
      Wt[(size_t)(n0 + n) * C_ + k0 + tx] = (_Float16)tile[tx][n];
    }
  } else {
    int i = (blk - 8192) * 256 + thr;  // 0..3071
    const float* s = (i < 1024) ? bq : ((i < 2048) ? bk : bv);
    b3[i] = s[i & 1023];
  }
}

// ---------------------------------------------------------------------------
// f16 MFMA GEMM: Out[M,N] = A[M,1024] @ Wt[N,1024]^T + bias.
// BK=32, 256 threads = 4 waves (2x2); wave tile (BM/2)x(BN/2).
// Staging via global_load_lds width=16 (m97 pattern).
// NEW (r10): bijective XCD swizzle (T1) -- each XCD gets a contiguous
// by-chunk so its A-slice (~1 MB) is L2-resident instead of round-robin
// panel spray (same remap that cut attn FETCH 69.7->12.3 MB in r5).
// EPI 0: fused QKV epilogue. Q (scaled 0.125*log2e) and K: plain 2-B stores.
// V: packed 8-B stores to V^T.  EPI 1: fp32 out + bias (of).
// ---------------------------------------------------------------------------
template <int BM, int BN, int EPI, int GX, int GY>
__global__ __launch_bounds__(256) void gemm_f16_kernel(
    const _Float16* __restrict__ A, const _Float16* __restrict__ Bw,
    const float* __restrict__ bias,
    _Float16* __restrict__ o0, _Float16* __restrict__ o1,
    _Float16* __restrict__ o2, float* __restrict__ of)
{
  constexpr int FM = BM / 32, FN = BN / 32;
  constexpr int NWG = GX * GY, CPX = NWG / 8;   // GX*GY divisible by 8
  __shared__ __align__(16) _Float16 As[BM * 32];
  __shared__ __align__(16) _Float16 Bs[BN * 32];
  const int t = threadIdx.x;
  const int w = t >> 6, lane = t & 63, l15 = lane & 15, quad = lane >> 4;
  const int wm = (w & 1) * (BM / 2), wn = (w >> 1) * (BN / 2);
  // XCD-aware bijective remap of the linear block id.
  const int lin = blockIdx.x + GX * blockIdx.y;
  const int swz = (lin & 7) * CPX + (lin >> 3);
  const int bxs = swz % GX, bys = swz / GX;
  const int bm = bys * BM, bn = bxs * BN;
  const int lrow = lane >> 2, lcol = (lane & 3) * 8;  // staging: 16 rows/call

  f32x4 acc[FM][FN];
#pragma unroll
  for (int i = 0; i < FM; i++)
#pragma unroll
    for (int j = 0; j < FN; j++) acc[i][j] = (f32x4){0.f, 0.f, 0.f, 0.f};

  for (int k0 = 0; k0 < 1024; k0 += 32) {
#pragma unroll
    for (int i = 0; i < BM / 64; i++) {
      int ca = w + 4 * i;
      int row = ca * 16 + lrow;
      GLD_LDS(A + (size_t)(bm + row) * 1024 + k0 + lcol, As + ca * 512);
    }
#pragma unroll
    for (int i = 0; i < BN / 64; i++) {
      int cb = w + 4 * i;
      int row = cb * 16 + lrow;
      GLD_LDS(Bw + (size_t)(bn + row) * 1024 + k0 + lcol, Bs + cb * 512);
    }
    __syncthreads();

    half8v af[FM], bf[FN];
#pragma unroll
    for (int mt = 0; mt < FM; mt++)
      af[mt] = *(const half8v*)(As + (wm + mt * 16 + l15) * 32 + quad * 8);
#pragma unroll
    for (int nt = 0; nt < FN; nt++)
      bf[nt] = *(const half8v*)(Bs + (wn + nt * 16 + l15) * 32 + quad * 8);
#pragma unroll
    for (int mt = 0; mt < FM; mt++)
#pragma unroll
      for (int nt = 0; nt < FN; nt++)
        acc[mt][nt] = __builtin_amdgcn_mfma_f32_16x16x32_f16(
            af[mt], bf[nt], acc[mt][nt], 0, 0, 0);
    __syncthreads();
  }

  // Epilogue. C/D layout: col = l15 (n), row = quad*4 + r (m).
#pragma unroll
  for (int mt = 0; mt < FM; mt++)
#pragma unroll
    for (int nt = 0; nt < FN; nt++) {
      int n = bn + wn + nt * 16 + l15;
      float bv = bias[n];
      if (EPI == 0 && bn >= 2048) {
        // V region: pack r=0..3 (consecutive t) -> one 8-B store to V^T.
        int dg = n - 2048;
        int hh = dg >> 6, hd = dg & 63;
        int m0 = bm + wm + mt * 16 + quad * 4;
        int bb = m0 >> 11, tt = m0 & 2047;
        half2v p01 = __builtin_bit_cast(half2v,
            __builtin_amdgcn_cvt_pkrtz(acc[mt][nt][0] + bv, acc[mt][nt][1] + bv));
        half2v p23 = __builtin_bit_cast(half2v,
            __builtin_amdgcn_cvt_pkrtz(acc[mt][nt][2] + bv, acc[mt][nt][3] + bv));
        half4v pk = __builtin_shufflevector(p01, p23, 0, 1, 2, 3);
        *(half4v*)(o2 + (((size_t)(bb * H_ + hh) * 64 + hd) * 2048 + tt)) = pk;
      } else {
#pragma unroll
        for (int r = 0; r < 4; r++) {
          int m = bm + wm + mt * 16 + quad * 4 + r;
          float v = acc[mt][nt][r] + bv;
          if (EPI == 0) {
            if (bn < 1024) {
              // Q pre-scaled by 0.125 * log2(e) for base-2 softmax.
              o0[(size_t)m * 1024 + n] = (_Float16)(v * 0.180336884f);
            } else {
              o1[(size_t)m * 1024 + (n - 1024)] = (_Float16)v;    // K
            }
          } else {
            of[(size_t)m * 1024 + n] = v;
          }
        }
      }
    }
}

// ---------------------------------------------------------------------------
// MFMA flash attention (no mask, per reference). Grid (T/128, H, B), 512 thr.
// V15 frame (round-6 best measured, 62.0 us) EXACTLY:
//  (a') PV 16x16x32 via dual-half4v V-operand, unpermuted S^T (r6).
//  (b) bijective XCD swizzle (r5: FETCH 69.7 -> 12.3 MB).
//  (c) s_setprio(1) around MFMA clusters (T5).
// Closed-out by measurement: T14 async/issue-early (r2/r3/r7/r8: neutral at
// best, 2.5x loss when loads get sunk), T13 defer-max & T17 max3 (r9: -3 us,
// VALUBusy UP from the added branch boundary). Staging latency is hidden by
// inter-wave overlap in this 2-barrier frame; softmax VALU phase is not
// compressible in-place.
// LDS: Ks[128][68] + Vs[64][132] = 34.3 KB (2 blocks/CU proven).
// Wave w (0..7) owns q-cols qt*128 + w*16 + l15. Base-2 softmax.
// ---------------------------------------------------------------------------
__global__ __launch_bounds__(512) void attn_f16_kernel(
    const _Float16* __restrict__ Qh, const _Float16* __restrict__ Kh,
    const _Float16* __restrict__ Vt, _Float16* __restrict__ Yh)
{
  __shared__ __align__(16) _Float16 Ks[128 * 68];   // [key][d], 136-B rows
  __shared__ __align__(16) _Float16 Vs[64 * 132];   // [d][t], 264-B rows
  const int t = threadIdx.x;
  const int w = t >> 6, lane = t & 63, l15 = lane & 15, quad = lane >> 4;
  // XCD-aware bijective remap of the 512 linear block ids (x fastest):
  // swz = (lin%8)*64 + lin/8 -> 64-consecutive-work chunks per XCD,
  // each chunk = 4 complete (b,h) groups (their K/V stay in one L2).
  const int lin = blockIdx.x + 16 * blockIdx.y + 256 * blockIdx.z;
  const int swz = (lin & 7) * 64 + (lin >> 3);
  const int qt = swz & 15, h = (swz >> 4) & 15, b = swz >> 8;
  const int qg = qt * 128 + w * 16 + l15;
  const size_t qoff = ((size_t)(b * T_ + qg)) * C_ + h * HD_;

  half8v qf[2];
  qf[0] = *(const half8v*)(Qh + qoff + quad * 8);
  qf[1] = *(const half8v*)(Qh + qoff + 32 + quad * 8);

  f32x4 o[4];
#pragma unroll
  for (int i = 0; i < 4; i++) o[i] = (f32x4){0.f, 0.f, 0.f, 0.f};
  float m_run = -INFINITY, l_run = 0.f;

  const size_t kbase = ((size_t)b * T_) * C_ + h * HD_;
  const size_t vbase = ((size_t)(b * H_ + h)) * HD_ * 2048;

  for (int kt0 = 0; kt0 < T_; kt0 += 128) {
    // Stage K: 128 keys x 64 d = 1024 16-B chunks (2 per thread).
#pragma unroll
    for (int i = 0; i < 2; i++) {
      int slot = t + i * 512;          // 0..1023
      int row = slot >> 3, cp = slot & 7;
      *(uint4*)((char*)Ks + row * 136 + cp * 16) =
          *(const uint4*)(Kh + kbase + (size_t)(kt0 + row) * C_ + cp * 8);
    }
    // Stage V^T: 64 d x 128 t = 1024 16-B chunks (2 per thread).
#pragma unroll
    for (int i = 0; i < 2; i++) {
      int slot = t + i * 512;          // 0..1023
      int row = slot >> 4, cp = slot & 15;
      *(uint4*)((char*)Vs + row * 264 + cp * 16) =
          *(const uint4*)(Vt + vbase + (size_t)row * 2048 + kt0 + cp * 8);
    }
    __syncthreads();

    // S^T tiles: 8 key-tiles x 2 d-steps of 16x16x32 (unpermuted).
    f32x4 s[8];
    __builtin_amdgcn_s_setprio(1);
#pragma unroll
    for (int kt = 0; kt < 8; kt++) {
      s[kt] = (f32x4){0.f, 0.f, 0.f, 0.f};
      int key = kt * 16 + l15;
#pragma unroll
      for (int ks = 0; ks < 2; ks++) {
        half8v kf = *(const half8v*)((char*)Ks + key * 136 + (ks * 4 + quad) * 16);
        s[kt] = __builtin_amdgcn_mfma_f32_16x16x32_f16(kf, qf[ks], s[kt], 0, 0, 0);
      }
    }
    __builtin_amdgcn_s_setprio(0);

    // Online softmax (base-2) over the 128 keys, per q column = l15.
    float tmax = -INFINITY;
#pragma unroll
    for (int kt = 0; kt < 8; kt++)
#pragma unroll
      for (int r = 0; r < 4; r++) tmax = fmaxf(tmax, s[kt][r]);
    tmax = fmaxf(tmax, __shfl_xor(tmax, 16));
    tmax = fmaxf(tmax, __shfl_xor(tmax, 32));
    float mnew = fmaxf(m_run, tmax);
    float alpha = __builtin_amdgcn_exp2f(m_run - mnew);

    float psum = 0.f;
    half4v pf[8];
#pragma unroll
    for (int kt = 0; kt < 8; kt++) {
      float p0 = __builtin_amdgcn_exp2f(s[kt][0] - mnew);
      float p1 = __builtin_amdgcn_exp2f(s[kt][1] - mnew);
      float p2 = __builtin_amdgcn_exp2f(s[kt][2] - mnew);
      float p3 = __builtin_amdgcn_exp2f(s[kt][3] - mnew);
      psum += (p0 + p1) + (p2 + p3);
      half2v pk01 = __builtin_bit_cast(half2v, __builtin_amdgcn_cvt_pkrtz(p0, p1));
      half2v pk23 = __builtin_bit_cast(half2v, __builtin_amdgcn_cvt_pkrtz(p2, p3));
      pf[kt] = __builtin_shufflevector(pk01, pk23, 0, 1, 2, 3);
    }
    psum += __shfl_xor(psum, 16);
    psum += __shfl_xor(psum, 32);
    l_run = l_run * alpha + psum;
    m_run = mnew;
#pragma unroll
    for (int dt = 0; dt < 4; dt++) o[dt] *= alpha;

    // PV: o^T[d][q] += V^T x P, 4 d-tiles x 4 key-groups of 16x16x32.
    // pf[2p] holds P[32p+4q+(0..3)][q], pf[2p+1] holds P[32p+16+4q+(0..3)][q]
    // -> concat is the x32 B-operand (k=8q+j). Matching V^T A-operand:
    // two half4v at d*264 + p*64 + q*8 (+32) -- same addresses round 1 read.
    __builtin_amdgcn_s_setprio(1);
#pragma unroll
    for (int dt = 0; dt < 4; dt++) {
      int d = dt * 16 + l15;
#pragma unroll
      for (int p = 0; p < 4; p++) {
        half4v v0 = *(const half4v*)((char*)Vs + d * 264 + p * 64 + quad * 8);
        half4v v1 = *(const half4v*)((char*)Vs + d * 264 + p * 64 + 32 + quad * 8);
        half8v vf = __builtin_shufflevector(v0, v1, 0, 1, 2, 3, 4, 5, 6, 7);
        half8v pf8 = __builtin_shufflevector(pf[2 * p], pf[2 * p + 1],
                                             0, 1, 2, 3, 4, 5, 6, 7);
        o[dt] = __builtin_amdgcn_mfma_f32_16x16x32_f16(vf, pf8, o[dt], 0, 0, 0);
      }
    }
    __builtin_amdgcn_s_setprio(0);
    __syncthreads();
  }

  float inv = 1.0f / l_run;
#pragma unroll
  for (int dt = 0; dt < 4; dt++) {
    half4v yv;
#pragma unroll
    for (int r = 0; r < 4; r++) yv[r] = (_Float16)(o[dt][r] * inv);
    *(half4v*)(Yh + qoff + dt * 16 + quad * 4) = yv;  // row q, cols h*64+d..
  }
}

// ---------------------------------------------------------------------------
extern "C" void kernel_launch(void* const* d_in, const int* in_sizes, int n_in,
                              void* d_out, int out_size, void* d_ws, size_t ws_size,
                              hipStream_t stream) {
  const float* x  = (const float*)d_in[0];
  const float* Wq = (const float*)d_in[1];
  const float* bq = (const float*)d_in[2];
  const float* Wk = (const float*)d_in[3];
  const float* bk = (const float*)d_in[4];
  const float* Wv = (const float*)d_in[5];
  const float* bv = (const float*)d_in[6];
  const float* Wo = (const float*)d_in[7];
  const float* bo = (const float*)d_in[8];
  float* out = (float*)d_out;

  // Workspace carve-up (bytes). Each f16 plane M_*C_ = 8 MB.
  char* ws = (char*)d_ws;
  _Float16* xh   = (_Float16*)(ws);                        // 8 MB
  _Float16* Qh   = (_Float16*)(ws + (((size_t)8)  << 20)); // 8 MB
  _Float16* Kh   = (_Float16*)(ws + (((size_t)16) << 20)); // 8 MB
  _Float16* Vt   = (_Float16*)(ws + (((size_t)24) << 20)); // 8 MB  [b,h,d,t]
  _Float16* Yh   = (_Float16*)(ws + (((size_t)32) << 20)); // 8 MB
  _Float16* Wt3  = (_Float16*)(ws + (((size_t)40) << 20)); // 6 MB  [3072][1024]
  _Float16* Wot  = (_Float16*)(ws + (((size_t)46) << 20)); // 2 MB  [1024][1024]
  float*    b3   = (float*)   (ws + (((size_t)48) << 20)); // 12 KB

  prep_kernel<<<8204, 256, 0, stream>>>(x, Wq, Wk, Wv, Wo, bq, bk, bv,
                                        xh, Wt3, Wot, b3);

  // Fused QKV projection: [4096,1024] @ [1024,3072] -> Q,K (f16) + V^T (f16).
  gemm_f16_kernel<128, 128, 0, 24, 32><<<dim3(24, 32), 256, 0, stream>>>(
      xh, Wt3, b3, Qh, Kh, Vt, nullptr);

  attn_f16_kernel<<<dim3(T_ / 128, H_, B_), 512, 0, stream>>>(Qh, Kh, Vt, Yh);

  // Output projection: Yh @ Wot^T + bo -> fp32 out.
  gemm_f16_kernel<64, 128, 1, 8, 64><<<dim3(8, 64), 256, 0, stream>>>(
      Yh, Wot, bo, nullptr, nullptr, nullptr, out);
}

// Round 11
// 195.740 us; speedup vs baseline: 1.0538x; 1.0027x over previous
//
#include <hip/hip_runtime.h>
#include <math.h>

#define B_ 2
#define T_ 2048
#define C_ 1024
#define H_ 16
#define HD_ 64
#define M_ (B_*T_)

typedef _Float16 half2v __attribute__((ext_vector_type(2)));
typedef _Float16 half4v __attribute__((ext_vector_type(4)));
typedef _Float16 half8v __attribute__((ext_vector_type(8)));
typedef float f32x4 __attribute__((ext_vector_type(4)));

#define GLD_LDS(gp, lp) \
  __builtin_amdgcn_global_load_lds( \
      (const __attribute__((address_space(1))) void*)(gp), \
      (__attribute__((address_space(3))) void*)(lp), 16, 0, 0)

// ---------------------------------------------------------------------------
// Fused prep: fp32->f16 cast of x (blocks 0..4095), 4 weight transposes
// (blocks 4096..8191), bias concat (blocks 8192..8203). One launch.
// ---------------------------------------------------------------------------
__global__ __launch_bounds__(256) void prep_kernel(
    const float* __restrict__ x,
    const float* __restrict__ Wq, const float* __restrict__ Wk,
    const float* __restrict__ Wv, const float* __restrict__ Wo,
    const float* __restrict__ bq, const float* __restrict__ bk,
    const float* __restrict__ bv,
    _Float16* __restrict__ xh, _Float16* __restrict__ Wt3,
    _Float16* __restrict__ Wot, float* __restrict__ b3)
{
  __shared__ float tile[32][33];
  const int blk = blockIdx.x, thr = threadIdx.x;
  if (blk < 4096) {
    int i = blk * 256 + thr;
    float4 v = ((const float4*)x)[i];
    half4v h; h[0] = (_Float16)v.x; h[1] = (_Float16)v.y;
    h[2] = (_Float16)v.z; h[3] = (_Float16)v.w;
    ((half4v*)xh)[i] = h;
  } else if (blk < 8192) {
    int zz = (blk - 4096) >> 10;      // which W
    int bxy = (blk - 4096) & 1023;
    const float* W; _Float16* Wt;
    switch (zz) {
      case 0:  W = Wq; Wt = Wt3; break;
      case 1:  W = Wk; Wt = Wt3 + (size_t)1024 * 1024; break;
      case 2:  W = Wv; Wt = Wt3 + (size_t)2048 * 1024; break;
      default: W = Wo; Wt = Wot; break;
    }
    const int n0 = (bxy & 31) * 32, k0 = (bxy >> 5) * 32;
    const int tx = thr & 31, ty = thr >> 5;  // 32 x 8
#pragma unroll
    for (int r = 0; r < 4; r++) {
      int k = ty + r * 8;
      tile[k][tx] = W[(size_t)(k0 + k) * C_ + n0 + tx];
    }
    __syncthreads();
#pragma unroll
    for (int r = 0; r < 4; r++) {
      int n = ty + r * 8;
      Wt[(size_t)(n0 + n) * C_ + k0 + tx] = (_Float16)tile[tx][n];
    }
  } else {
    int i = (blk - 8192) * 256 + thr;  // 0..3071
    const float* s = (i < 1024) ? bq : ((i < 2048) ? bk : bv);
    b3[i] = s[i & 1023];
  }
}

// ---------------------------------------------------------------------------
// f16 MFMA GEMM: Out[M,N] = A[M,1024] @ Wt[N,1024]^T + bias.
// r11: effective BK=64 via TWO 32-wide K-slice buffers per barrier pair:
// 8 GLD -> barrier -> 32 MFMA -> barrier, 16 iterations (was 32). Halves the
// vmcnt+barrier drains (m98: ~20% of GEMM time) while keeping each buffer's
// row stride at 64 B (2-way LDS conflict = free); a true [128][64] tile
// would be a 16-way conflict on the b128 frag reads, unpaddable under
// global_load_lds. MFMA halves processed sequentially to bound VGPRs.
// 256 threads = 4 waves (2x2); wave tile (BM/2)x(BN/2); LDS 32 KB.
// r10: bijective XCD swizzle (T1) -- contiguous by-chunks per XCD.
// EPI 0: fused QKV epilogue. Q (scaled 0.125*log2e) and K: plain 2-B stores.
// V: packed 8-B stores to V^T.  EPI 1: fp32 out + bias (of).
// ---------------------------------------------------------------------------
template <int BM, int BN, int EPI, int GX, int GY>
__global__ __launch_bounds__(256) void gemm_f16_kernel(
    const _Float16* __restrict__ A, const _Float16* __restrict__ Bw,
    const float* __restrict__ bias,
    _Float16* __restrict__ o0, _Float16* __restrict__ o1,
    _Float16* __restrict__ o2, float* __restrict__ of)
{
  constexpr int FM = BM / 32, FN = BN / 32;
  constexpr int NWG = GX * GY, CPX = NWG / 8;   // GX*GY divisible by 8
  __shared__ __align__(16) _Float16 As[2 * BM * 32];
  __shared__ __align__(16) _Float16 Bs[2 * BN * 32];
  const int t = threadIdx.x;
  const int w = t >> 6, lane = t & 63, l15 = lane & 15, quad = lane >> 4;
  const int wm = (w & 1) * (BM / 2), wn = (w >> 1) * (BN / 2);
  // XCD-aware bijective remap of the linear block id.
  const int lin = blockIdx.x + GX * blockIdx.y;
  const int swz = (lin & 7) * CPX + (lin >> 3);
  const int bxs = swz % GX, bys = swz / GX;
  const int bm = bys * BM, bn = bxs * BN;
  const int lrow = lane >> 2, lcol = (lane & 3) * 8;  // staging: 16 rows/call

  f32x4 acc[FM][FN];
#pragma unroll
  for (int i = 0; i < FM; i++)
#pragma unroll
    for (int j = 0; j < FN; j++) acc[i][j] = (f32x4){0.f, 0.f, 0.f, 0.f};

  for (int k0 = 0; k0 < 1024; k0 += 64) {
#pragma unroll
    for (int hf = 0; hf < 2; hf++) {
#pragma unroll
      for (int i = 0; i < BM / 64; i++) {
        int ca = w + 4 * i;
        int row = ca * 16 + lrow;
        GLD_LDS(A + (size_t)(bm + row) * 1024 + k0 + hf * 32 + lcol,
                As + hf * BM * 32 + ca * 512);
      }
#pragma unroll
      for (int i = 0; i < BN / 64; i++) {
        int cb = w + 4 * i;
        int row = cb * 16 + lrow;
        GLD_LDS(Bw + (size_t)(bn + row) * 1024 + k0 + hf * 32 + lcol,
                Bs + hf * BN * 32 + cb * 512);
      }
    }
    __syncthreads();

#pragma unroll
    for (int hf = 0; hf < 2; hf++) {
      half8v af[FM], bf[FN];
#pragma unroll
      for (int mt = 0; mt < FM; mt++)
        af[mt] = *(const half8v*)(As + hf * BM * 32 +
                                  (wm + mt * 16 + l15) * 32 + quad * 8);
#pragma unroll
      for (int nt = 0; nt < FN; nt++)
        bf[nt] = *(const half8v*)(Bs + hf * BN * 32 +
                                  (wn + nt * 16 + l15) * 32 + quad * 8);
#pragma unroll
      for (int mt = 0; mt < FM; mt++)
#pragma unroll
        for (int nt = 0; nt < FN; nt++)
          acc[mt][nt] = __builtin_amdgcn_mfma_f32_16x16x32_f16(
              af[mt], bf[nt], acc[mt][nt], 0, 0, 0);
    }
    __syncthreads();
  }

  // Epilogue. C/D layout: col = l15 (n), row = quad*4 + r (m).
#pragma unroll
  for (int mt = 0; mt < FM; mt++)
#pragma unroll
    for (int nt = 0; nt < FN; nt++) {
      int n = bn + wn + nt * 16 + l15;
      float bv = bias[n];
      if (EPI == 0 && bn >= 2048) {
        // V region: pack r=0..3 (consecutive t) -> one 8-B store to V^T.
        int dg = n - 2048;
        int hh = dg >> 6, hd = dg & 63;
        int m0 = bm + wm + mt * 16 + quad * 4;
        int bb = m0 >> 11, tt = m0 & 2047;
        half2v p01 = __builtin_bit_cast(half2v,
            __builtin_amdgcn_cvt_pkrtz(acc[mt][nt][0] + bv, acc[mt][nt][1] + bv));
        half2v p23 = __builtin_bit_cast(half2v,
            __builtin_amdgcn_cvt_pkrtz(acc[mt][nt][2] + bv, acc[mt][nt][3] + bv));
        half4v pk = __builtin_shufflevector(p01, p23, 0, 1, 2, 3);
        *(half4v*)(o2 + (((size_t)(bb * H_ + hh) * 64 + hd) * 2048 + tt)) = pk;
      } else {
#pragma unroll
        for (int r = 0; r < 4; r++) {
          int m = bm + wm + mt * 16 + quad * 4 + r;
          float v = acc[mt][nt][r] + bv;
          if (EPI == 0) {
            if (bn < 1024) {
              // Q pre-scaled by 0.125 * log2(e) for base-2 softmax.
              o0[(size_t)m * 1024 + n] = (_Float16)(v * 0.180336884f);
            } else {
              o1[(size_t)m * 1024 + (n - 1024)] = (_Float16)v;    // K
            }
          } else {
            of[(size_t)m * 1024 + n] = v;
          }
        }
      }
    }
}

// ---------------------------------------------------------------------------
// MFMA flash attention (no mask, per reference). Grid (T/128, H, B), 512 thr.
// V15 frame (round-6/10 best measured, 61.8 us) EXACTLY:
//  (a') PV 16x16x32 via dual-half4v V-operand, unpermuted S^T (r6).
//  (b) bijective XCD swizzle (r5: FETCH 69.7 -> 12.3 MB).
//  (c) s_setprio(1) around MFMA clusters (T5).
// Closed-out by measurement: T14 async/issue-early (r2/r3/r7/r8), T13/T17
// (r9). Remaining 40% stall = barrier convoy at problem-capped grid
// (512 blocks = exactly 2/CU); not addressable in-frame.
// LDS: Ks[128][68] + Vs[64][132] = 34.3 KB (2 blocks/CU proven).
// Wave w (0..7) owns q-cols qt*128 + w*16 + l15. Base-2 softmax.
// ---------------------------------------------------------------------------
__global__ __launch_bounds__(512) void attn_f16_kernel(
    const _Float16* __restrict__ Qh, const _Float16* __restrict__ Kh,
    const _Float16* __restrict__ Vt, _Float16* __restrict__ Yh)
{
  __shared__ __align__(16) _Float16 Ks[128 * 68];   // [key][d], 136-B rows
  __shared__ __align__(16) _Float16 Vs[64 * 132];   // [d][t], 264-B rows
  const int t = threadIdx.x;
  const int w = t >> 6, lane = t & 63, l15 = lane & 15, quad = lane >> 4;
  // XCD-aware bijective remap of the 512 linear block ids (x fastest):
  // swz = (lin%8)*64 + lin/8 -> 64-consecutive-work chunks per XCD,
  // each chunk = 4 complete (b,h) groups (their K/V stay in one L2).
  const int lin = blockIdx.x + 16 * blockIdx.y + 256 * blockIdx.z;
  const int swz = (lin & 7) * 64 + (lin >> 3);
  const int qt = swz & 15, h = (swz >> 4) & 15, b = swz >> 8;
  const int qg = qt * 128 + w * 16 + l15;
  const size_t qoff = ((size_t)(b * T_ + qg)) * C_ + h * HD_;

  half8v qf[2];
  qf[0] = *(const half8v*)(Qh + qoff + quad * 8);
  qf[1] = *(const half8v*)(Qh + qoff + 32 + quad * 8);

  f32x4 o[4];
#pragma unroll
  for (int i = 0; i < 4; i++) o[i] = (f32x4){0.f, 0.f, 0.f, 0.f};
  float m_run = -INFINITY, l_run = 0.f;

  const size_t kbase = ((size_t)b * T_) * C_ + h * HD_;
  const size_t vbase = ((size_t)(b * H_ + h)) * HD_ * 2048;

  for (int kt0 = 0; kt0 < T_; kt0 += 128) {
    // Stage K: 128 keys x 64 d = 1024 16-B chunks (2 per thread).
#pragma unroll
    for (int i = 0; i < 2; i++) {
      int slot = t + i * 512;          // 0..1023
      int row = slot >> 3, cp = slot & 7;
      *(uint4*)((char*)Ks + row * 136 + cp * 16) =
          *(const uint4*)(Kh + kbase + (size_t)(kt0 + row) * C_ + cp * 8);
    }
    // Stage V^T: 64 d x 128 t = 1024 16-B chunks (2 per thread).
#pragma unroll
    for (int i = 0; i < 2; i++) {
      int slot = t + i * 512;          // 0..1023
      int row = slot >> 4, cp = slot & 15;
      *(uint4*)((char*)Vs + row * 264 + cp * 16) =
          *(const uint4*)(Vt + vbase + (size_t)row * 2048 + kt0 + cp * 8);
    }
    __syncthreads();

    // S^T tiles: 8 key-tiles x 2 d-steps of 16x16x32 (unpermuted).
    f32x4 s[8];
    __builtin_amdgcn_s_setprio(1);
#pragma unroll
    for (int kt = 0; kt < 8; kt++) {
      s[kt] = (f32x4){0.f, 0.f, 0.f, 0.f};
      int key = kt * 16 + l15;
#pragma unroll
      for (int ks = 0; ks < 2; ks++) {
        half8v kf = *(const half8v*)((char*)Ks + key * 136 + (ks * 4 + quad) * 16);
        s[kt] = __builtin_amdgcn_mfma_f32_16x16x32_f16(kf, qf[ks], s[kt], 0, 0, 0);
      }
    }
    __builtin_amdgcn_s_setprio(0);

    // Online softmax (base-2) over the 128 keys, per q column = l15.
    float tmax = -INFINITY;
#pragma unroll
    for (int kt = 0; kt < 8; kt++)
#pragma unroll
      for (int r = 0; r < 4; r++) tmax = fmaxf(tmax, s[kt][r]);
    tmax = fmaxf(tmax, __shfl_xor(tmax, 16));
    tmax = fmaxf(tmax, __shfl_xor(tmax, 32));
    float mnew = fmaxf(m_run, tmax);
    float alpha = __builtin_amdgcn_exp2f(m_run - mnew);

    float psum = 0.f;
    half4v pf[8];
#pragma unroll
    for (int kt = 0; kt < 8; kt++) {
      float p0 = __builtin_amdgcn_exp2f(s[kt][0] - mnew);
      float p1 = __builtin_amdgcn_exp2f(s[kt][1] - mnew);
      float p2 = __builtin_amdgcn_exp2f(s[kt][2] - mnew);
      float p3 = __builtin_amdgcn_exp2f(s[kt][3] - mnew);
      psum += (p0 + p1) + (p2 + p3);
      half2v pk01 = __builtin_bit_cast(half2v, __builtin_amdgcn_cvt_pkrtz(p0, p1));
      half2v pk23 = __builtin_bit_cast(half2v, __builtin_amdgcn_cvt_pkrtz(p2, p3));
      pf[kt] = __builtin_shufflevector(pk01, pk23, 0, 1, 2, 3);
    }
    psum += __shfl_xor(psum, 16);
    psum += __shfl_xor(psum, 32);
    l_run = l_run * alpha + psum;
    m_run = mnew;
#pragma unroll
    for (int dt = 0; dt < 4; dt++) o[dt] *= alpha;

    // PV: o^T[d][q] += V^T x P, 4 d-tiles x 4 key-groups of 16x16x32.
    // pf[2p] holds P[32p+4q+(0..3)][q], pf[2p+1] holds P[32p+16+4q+(0..3)][q]
    // -> concat is the x32 B-operand (k=8q+j). Matching V^T A-operand:
    // two half4v at d*264 + p*64 + q*8 (+32) -- same addresses round 1 read.
    __builtin_amdgcn_s_setprio(1);
#pragma unroll
    for (int dt = 0; dt < 4; dt++) {
      int d = dt * 16 + l15;
#pragma unroll
      for (int p = 0; p < 4; p++) {
        half4v v0 = *(const half4v*)((char*)Vs + d * 264 + p * 64 + quad * 8);
        half4v v1 = *(const half4v*)((char*)Vs + d * 264 + p * 64 + 32 + quad * 8);
        half8v vf = __builtin_shufflevector(v0, v1, 0, 1, 2, 3, 4, 5, 6, 7);
        half8v pf8 = __builtin_shufflevector(pf[2 * p], pf[2 * p + 1],
                                             0, 1, 2, 3, 4, 5, 6, 7);
        o[dt] = __builtin_amdgcn_mfma_f32_16x16x32_f16(vf, pf8, o[dt], 0, 0, 0);
      }
    }
    __builtin_amdgcn_s_setprio(0);
    __syncthreads();
  }

  float inv = 1.0f / l_run;
#pragma unroll
  for (int dt = 0; dt < 4; dt++) {
    half4v yv;
#pragma unroll
    for (int r = 0; r < 4; r++) yv[r] = (_Float16)(o[dt][r] * inv);
    *(half4v*)(Yh + qoff + dt * 16 + quad * 4) = yv;  // row q, cols h*64+d..
  }
}

// ---------------------------------------------------------------------------
extern "C" void kernel_launch(void* const* d_in, const int* in_sizes, int n_in,
                              void* d_out, int out_size, void* d_ws, size_t ws_size,
                              hipStream_t stream) {
  const float* x  = (const float*)d_in[0];
  const float* Wq = (const float*)d_in[1];
  const float* bq = (const float*)d_in[2];
  const float* Wk = (const float*)d_in[3];
  const float* bk = (const float*)d_in[4];
  const float* Wv = (const float*)d_in[5];
  const float* bv = (const float*)d_in[6];
  const float* Wo = (const float*)d_in[7];
  const float* bo = (const float*)d_in[8];
  float* out = (float*)d_out;

  // Workspace carve-up (bytes). Each f16 plane M_*C_ = 8 MB.
  char* ws = (char*)d_ws;
  _Float16* xh   = (_Float16*)(ws);                        // 8 MB
  _Float16* Qh   = (_Float16*)(ws + (((size_t)8)  << 20)); // 8 MB
  _Float16* Kh   = (_Float16*)(ws + (((size_t)16) << 20)); // 8 MB
  _Float16* Vt   = (_Float16*)(ws + (((size_t)24) << 20)); // 8 MB  [b,h,d,t]
  _Float16* Yh   = (_Float16*)(ws + (((size_t)32) << 20)); // 8 MB
  _Float16* Wt3  = (_Float16*)(ws + (((size_t)40) << 20)); // 6 MB  [3072][1024]
  _Float16* Wot  = (_Float16*)(ws + (((size_t)46) << 20)); // 2 MB  [1024][1024]
  float*    b3   = (float*)   (ws + (((size_t)48) << 20)); // 12 KB

  prep_kernel<<<8204, 256, 0, stream>>>(x, Wq, Wk, Wv, Wo, bq, bk, bv,
                                        xh, Wt3, Wot, b3);

  // Fused QKV projection: [4096,1024] @ [1024,3072] -> Q,K (f16) + V^T (f16).
  gemm_f16_kernel<128, 128, 0, 24, 32><<<dim3(24, 32), 256, 0, stream>>>(
      xh, Wt3, b3, Qh, Kh, Vt, nullptr);

  attn_f16_kernel<<<dim3(T_ / 128, H_, B_), 512, 0, stream>>>(Qh, Kh, Vt, Yh);

  // Output projection: Yh @ Wot^T + bo -> fp32 out.
  gemm_f16_kernel<64, 128, 1, 8, 64><<<dim3(8, 64), 256, 0, stream>>>(
      Yh, Wot, bo, nullptr, nullptr, nullptr, out);
}